// Round 7
// baseline (127.652 us; speedup 1.0000x reference)
//
#include <hip/hip_runtime.h>

// AttentionLayer: out = softmax(Q @ V^T) @ V ; B=4, SQ=SKV=4096, D=64, fp32.
//
// R4-R6: transposed formulation kills the P LDS round-trip.
//   S^T = V·Q^T via 16x16x32 (A=V tile, B=Q regs) -> C holds S^T[kv][q].
//   For 16x16x16 MFMA, C-layout k-positions (quad*4+r) == A/B-operand
//   k-positions (quad*4+j), so exp2(S^T) fragments feed DIRECTLY as the
//   B-operand of O^T = V^T·P^T (K=16). No LDS transform, no u16 gathers.
//   Softmax m/l are per-lane scalars; cross-lane max = 2 shuffles (xor 16,32).
//   LDS: double-buffered {V, V^T} tiles (36.9 KB, 4 blocks/CU), ONE barrier
//   per iter; staging loads issued after the barrier, hidden under compute.
//   Epilogue transposes O^T through the freed LDS so po stays [q][d].
// R6 fix: legacy K=16 fp16 MFMA builtin is ..._16x16x16f16 (no underscore
// before f16 on the carried-forward CDNA1-era intrinsics; only the
// gfx950-new K=32 ones have it).

#define NB   4
#define SQ   4096
#define SKV  4096
#define DH   64
#define L2E  1.44269504088896340736f

typedef _Float16 half8 __attribute__((ext_vector_type(8)));
typedef _Float16 half4 __attribute__((ext_vector_type(4)));
typedef _Float16 half2v __attribute__((ext_vector_type(2)));
typedef float f32x4 __attribute__((ext_vector_type(4)));
typedef unsigned short u16;

#define MFMA16(a, b, c) __builtin_amdgcn_mfma_f32_16x16x16f16((a), (b), (c), 0, 0, 0)
#define MFMA32(a, b, c) __builtin_amdgcn_mfma_f32_16x16x32_f16((a), (b), (c), 0, 0, 0)

__device__ __forceinline__ u16 f2h(float f) {
  _Float16 h = (_Float16)f;
  return __builtin_bit_cast(u16, h);
}
__device__ __forceinline__ half2v pkrtz(float a, float b) {
  return __builtin_bit_cast(half2v, __builtin_amdgcn_cvt_pkrtz(a, b));
}

// ---------------------------------------------------------------- prep ----
// V fp32 -> vh fp16 [b][j][d] and vt fp16 [b][d][j]. grid NB*256, 256 thr.
__global__ __launch_bounds__(256) void prep_kernel(
    const float* __restrict__ V, u16* __restrict__ vh, u16* __restrict__ vt) {
  __shared__ u16 ldsT[16 * 72];
  int blk = blockIdx.x;
  int b   = blk >> 8;
  int rem = blk & 255;
  int j0  = (rem >> 2) << 6;   // kv tile base
  int d0  = (rem & 3) << 4;    // d tile base
  int t   = threadIdx.x;
  int j   = t >> 2;            // 0..63
  int dc  = (t & 3) << 2;      // 0,4,8,12

  const float* src = V + ((size_t)(b * SKV) + j0 + j) * DH + d0 + dc;
  float4 v4 = *(const float4*)src;
  u16 h[4] = {f2h(v4.x), f2h(v4.y), f2h(v4.z), f2h(v4.w)};
  unsigned p0 = (unsigned)h[0] | ((unsigned)h[1] << 16);
  unsigned p1 = (unsigned)h[2] | ((unsigned)h[3] << 16);
  size_t go = ((size_t)(b * SKV) + j0 + j) * DH + d0 + dc;
  *(uint2*)(vh + go) = make_uint2(p0, p1);

#pragma unroll
  for (int k = 0; k < 4; ++k) ldsT[(dc + k) * 72 + j] = h[k];
  __syncthreads();

  int dl = t >> 4;             // 0..15
  int jc = (t & 15) << 2;      // 0..60
  u16 tr[4];
#pragma unroll
  for (int k = 0; k < 4; ++k) tr[k] = ldsT[dl * 72 + jc + k];
  unsigned q0 = (unsigned)tr[0] | ((unsigned)tr[1] << 16);
  unsigned q1 = (unsigned)tr[2] | ((unsigned)tr[3] << 16);
  *(uint2*)(vt + ((size_t)(b * DH) + d0 + dl) * SKV + j0 + jc) = make_uint2(q0, q1);
}

// ---------------------------------------------------------------- attn ----
// grid NB*32*S blocks, 256 threads = 4 waves * 32 q-cols (2 sets of 16).
__global__ __launch_bounds__(256, 4) void attn_kernel(
    const float* __restrict__ Q,
    const u16* __restrict__ vh,
    const u16* __restrict__ vt,
    u16* __restrict__ po,    // [NB*32*S][128 q][64 d] fp16 unnormalized O
    float* __restrict__ pm,  // [NB*32*S][128] running max (log2 domain)
    float* __restrict__ pl,  // [NB*32*S][128] running sum
    int S, int kvLen) {
  // [buf][0 = V tile [kv][d], 1 = V^T tile [d][kv]], stride 72 (pad)
  __shared__ __align__(16) u16 lds[2][2][64 * 72];

  int blk  = blockIdx.x;
  int tile = blk / S;          // b*32 + qtile
  int s    = blk - tile * S;
  int b    = tile >> 5;
  int q0   = (tile & 31) << 7;
  int kv0  = s * kvLen;
  int t    = threadIdx.x;
  int wave = t >> 6;
  int lane = t & 63;
  int col  = lane & 15;
  int quad = lane >> 4;
  int qw   = q0 + (wave << 5);

  // ---- Q fragments as B-operand (n=lane&15=q, k=quad*8+j), log2e folded
  half8 qf[2][2];
#pragma unroll
  for (int set = 0; set < 2; ++set) {
#pragma unroll
    for (int kc = 0; kc < 2; ++kc) {
      const float* qp = Q + ((size_t)(b * SQ) + qw + set * 16 + col) * DH +
                        kc * 32 + (quad << 3);
      float4 a0 = *(const float4*)qp;
      float4 a1 = *(const float4*)(qp + 4);
      half8 h;
      h[0] = (_Float16)(a0.x * L2E); h[1] = (_Float16)(a0.y * L2E);
      h[2] = (_Float16)(a0.z * L2E); h[3] = (_Float16)(a0.w * L2E);
      h[4] = (_Float16)(a1.x * L2E); h[5] = (_Float16)(a1.y * L2E);
      h[6] = (_Float16)(a1.z * L2E); h[7] = (_Float16)(a1.w * L2E);
      qf[set][kc] = h;
    }
  }

  f32x4 o[2][4];               // O^T frags: [set][d-block], row=d, col=q
  float m_r[2] = {-1e30f, -1e30f};
  float l_r[2] = {0.f, 0.f};   // per-lane partial (this quad's kv rows)
#pragma unroll
  for (int set = 0; set < 2; ++set)
#pragma unroll
    for (int nf = 0; nf < 4; ++nf) o[set][nf] = (f32x4){0.f, 0.f, 0.f, 0.f};

  int sr = t >> 2;             // staging row 0..63
  int sc = (t & 3) << 4;       // staging col chunk
  const u16* gv  = vh + (size_t)(b * SKV) * DH;
  const u16* gvt = vt + (size_t)(b * DH) * SKV;
  int l0 = sr * 72 + sc;

  // prologue: stage tile 0 into buf 0
  {
    size_t g  = (size_t)(kv0 + sr) * DH + sc;
    size_t gt = (size_t)sr * SKV + kv0 + sc;
    *(uint4*)(&lds[0][0][l0])     = *(const uint4*)(gv + g);
    *(uint4*)(&lds[0][0][l0 + 8]) = *(const uint4*)(gv + g + 8);
    *(uint4*)(&lds[0][1][l0])     = *(const uint4*)(gvt + gt);
    *(uint4*)(&lds[0][1][l0 + 8]) = *(const uint4*)(gvt + gt + 8);
  }

  int nIter = kvLen >> 6;
  int cur = 0;
  for (int it = 0; it < nIter; ++it) {
    __syncthreads();           // buf(cur) ready; all waves done with buf(cur^1)

    uint4 a0, a1, c0, c1;
    bool more = (it + 1) < nIter;
    if (more) {                // issue next-tile loads AFTER barrier
      int j0 = kv0 + ((it + 1) << 6);
      size_t g  = (size_t)(j0 + sr) * DH + sc;
      size_t gt = (size_t)sr * SKV + j0 + sc;
      a0 = *(const uint4*)(gv + g);
      a1 = *(const uint4*)(gv + g + 8);
      c0 = *(const uint4*)(gvt + gt);
      c1 = *(const uint4*)(gvt + gt + 8);
    }
    const u16* sv  = &lds[cur][0][0];
    const u16* svt = &lds[cur][1][0];

    // ---- S^T = V @ Q^T (A = V tile from LDS, B = Q regs)
    f32x4 sf[2][4];
#pragma unroll
    for (int set = 0; set < 2; ++set)
#pragma unroll
      for (int nf = 0; nf < 4; ++nf) sf[set][nf] = (f32x4){0.f, 0.f, 0.f, 0.f};
#pragma unroll
    for (int nf = 0; nf < 4; ++nf) {
#pragma unroll
      for (int kc = 0; kc < 2; ++kc) {
        half8 av = *(const half8*)(sv + (nf * 16 + col) * 72 + kc * 32 + (quad << 3));
        sf[0][nf] = MFMA32(av, qf[0][kc], sf[0][nf]);
        sf[1][nf] = MFMA32(av, qf[1][kc], sf[1][nf]);
      }
    }

    // ---- online softmax (per-lane scalar state) + direct P^T B-frags
    half4 pf[2][4];
#pragma unroll
    for (int set = 0; set < 2; ++set) {
      float tm = sf[set][0][0];
#pragma unroll
      for (int nf = 0; nf < 4; ++nf)
#pragma unroll
        for (int r = 0; r < 4; ++r) tm = fmaxf(tm, sf[set][nf][r]);
      tm = fmaxf(tm, __shfl_xor(tm, 16, 64));
      tm = fmaxf(tm, __shfl_xor(tm, 32, 64));
      float mn = fmaxf(m_r[set], tm);
      float al = exp2f(m_r[set] - mn);
      m_r[set] = mn;
      float rs = 0.f;
#pragma unroll
      for (int nf = 0; nf < 4; ++nf) {
        float p0 = exp2f(sf[set][nf][0] - mn);
        float p1 = exp2f(sf[set][nf][1] - mn);
        float p2 = exp2f(sf[set][nf][2] - mn);
        float p3 = exp2f(sf[set][nf][3] - mn);
        rs += (p0 + p1) + (p2 + p3);
        half2v lo = pkrtz(p0, p1);
        half2v hi = pkrtz(p2, p3);
        pf[set][nf] = __builtin_shufflevector(lo, hi, 0, 1, 2, 3);
      }
      l_r[set] = l_r[set] * al + rs;
#pragma unroll
      for (int nf = 0; nf < 4; ++nf)
#pragma unroll
        for (int r = 0; r < 4; ++r) o[set][nf][r] *= al;
    }

    // ---- O^T += V^T @ P^T (K=16; P^T frags straight from C-layout)
#pragma unroll
    for (int kc4 = 0; kc4 < 4; ++kc4) {
#pragma unroll
      for (int nf2 = 0; nf2 < 4; ++nf2) {
        half4 avt = *(const half4*)(svt + (nf2 * 16 + col) * 72 + kc4 * 16 + (quad << 2));
        o[0][nf2] = MFMA16(avt, pf[0][kc4], o[0][nf2]);
        o[1][nf2] = MFMA16(avt, pf[1][kc4], o[1][nf2]);
      }
    }

    if (more) {                // write staged regs -> other buffer
      u16* dv  = &lds[cur ^ 1][0][0];
      u16* dvt = &lds[cur ^ 1][1][0];
      *(uint4*)(dv + l0)      = a0;
      *(uint4*)(dv + l0 + 8)  = a1;
      *(uint4*)(dvt + l0)     = c0;
      *(uint4*)(dvt + l0 + 8) = c1;
    }
    cur ^= 1;
  }

  // ---- epilogue: finish l across quads, transpose O^T -> po[q][d] via LDS
#pragma unroll
  for (int set = 0; set < 2; ++set) {
    l_r[set] += __shfl_xor(l_r[set], 16, 64);
    l_r[set] += __shfl_xor(l_r[set], 32, 64);
  }
  int pidx = tile * S + s;
  if (quad == 0) {
#pragma unroll
    for (int set = 0; set < 2; ++set) {
      int row = (wave << 5) + set * 16 + col;
      pm[(size_t)pidx * 128 + row] = m_r[set];
      pl[(size_t)pidx * 128 + row] = l_r[set];
    }
  }

  __syncthreads();             // done with tile buffers; reuse as 128x72 tile
  u16* tp = &lds[0][0][0];
#pragma unroll
  for (int set = 0; set < 2; ++set) {
    int q = (wave << 5) + set * 16 + col;
#pragma unroll
    for (int nf2 = 0; nf2 < 4; ++nf2) {
#pragma unroll
      for (int r2 = 0; r2 < 4; r2 += 2) {
        unsigned pk = (unsigned)f2h(o[set][nf2][r2]) |
                      ((unsigned)f2h(o[set][nf2][r2 + 1]) << 16);
        int d = nf2 * 16 + (quad << 2) + r2;
        *(unsigned*)(tp + q * 72 + d) = pk;
      }
    }
  }
  __syncthreads();
  {
    u16* pob = po + (size_t)pidx * 128 * 64;
    int q = t >> 1, hc = (t & 1) << 5;
    uint4 x0 = *(const uint4*)(tp + q * 72 + hc);
    uint4 x1 = *(const uint4*)(tp + q * 72 + hc + 8);
    uint4 x2 = *(const uint4*)(tp + q * 72 + hc + 16);
    uint4 x3 = *(const uint4*)(tp + q * 72 + hc + 24);
    *(uint4*)(pob + q * 64 + hc)      = x0;
    *(uint4*)(pob + q * 64 + hc + 8)  = x1;
    *(uint4*)(pob + q * 64 + hc + 16) = x2;
    *(uint4*)(pob + q * 64 + hc + 24) = x3;
  }
}

// ------------------------------------------------------------- combine ----
// grid NB*SQ/32 blocks, 256 threads; thread = (row, 8-d chunk).
__global__ __launch_bounds__(256) void combine_kernel(
    const u16* __restrict__ po,
    const float* __restrict__ pm,
    const float* __restrict__ pl,
    float* __restrict__ out, int S) {
  int t    = threadIdx.x;
  int rowg = blockIdx.x * 32 + (t >> 3);
  int tile = rowg >> 7;
  int row  = rowg & 127;
  int dc   = (t & 7) << 3;

  float mv[8], lv[8];
  float M = -1e30f;
  for (int s = 0; s < S; ++s) {
    mv[s] = pm[(size_t)(tile * S + s) * 128 + row];
    lv[s] = pl[(size_t)(tile * S + s) * 128 + row];
    M = fmaxf(M, mv[s]);
  }
  float L = 0.f, w[8];
  for (int s = 0; s < S; ++s) {
    w[s] = exp2f(mv[s] - M);
    L += lv[s] * w[s];
  }
  float acc[8] = {0.f, 0.f, 0.f, 0.f, 0.f, 0.f, 0.f, 0.f};
  for (int s = 0; s < S; ++s) {
    const u16* p = po + (size_t)(tile * S + s) * 8192 + row * 64 + dc;
    uint4 raw = *(const uint4*)p;
    half8 x = __builtin_bit_cast(half8, raw);
#pragma unroll
    for (int k = 0; k < 8; ++k) acc[k] += w[s] * (float)x[k];
  }
  float invL = 1.0f / L;
  float* op = out + (size_t)rowg * 64 + dc;
  f32x4 o0 = (f32x4){acc[0], acc[1], acc[2], acc[3]};
  f32x4 o1 = (f32x4){acc[4], acc[5], acc[6], acc[7]};
  *(f32x4*)op       = o0 * invL;
  *(f32x4*)(op + 4) = o1 * invL;
}

// -------------------------------------------------------------- launch ----
extern "C" void kernel_launch(void* const* d_in, const int* in_sizes, int n_in,
                              void* d_out, int out_size, void* d_ws, size_t ws_size,
                              hipStream_t stream) {
  const float* Q = (const float*)d_in[0];
  const float* V = (const float*)d_in[1];
  float* out = (float*)d_out;

  const size_t convBytes = (size_t)2 * NB * SKV * DH * 2;  // vh+vt = 4 MB
  auto partBytes = [](int S) {
    return (size_t)NB * 32 * S * ((size_t)128 * 64 * 2 + 128 * 8);
  };
  int S = 8;
  while (S > 1 && ws_size < convBytes + partBytes(S)) S >>= 1;
  int kvLen = SKV / S;

  u16* vh = (u16*)d_ws;
  u16* vt = vh + (size_t)NB * SKV * DH;
  u16* po = vt + (size_t)NB * SKV * DH;
  float* pm = (float*)(po + (size_t)NB * 32 * S * 128 * 64);
  float* pl = pm + (size_t)NB * 32 * S * 128;

  prep_kernel<<<NB * 256, 256, 0, stream>>>(V, vh, vt);
  attn_kernel<<<NB * 32 * S, 256, 0, stream>>>(Q, vh, vt, po, pm, pl, S, kvLen);
  combine_kernel<<<NB * SQ / 32, 256, 0, stream>>>(po, pm, pl, out, S);
}

// Round 8
// 111.906 us; speedup vs baseline: 1.1407x; 1.1407x over previous
//
#include <hip/hip_runtime.h>

// AttentionLayer: out = softmax(Q @ V^T) @ V ; B=4, SQ=SKV=4096, D=64, fp32.
//
// R4-R6: transposed formulation (S^T = V·Q^T; exp2 C-frags feed K=16 PV MFMA
// directly as B-operand; per-lane scalar softmax state; double-buffered LDS,
// one barrier/iter).
// R7 fix: R6's staged uint4 regs (16 VGPRs) lived across the whole compute
// body -> scratch spill (WRITE_SIZE 19->132 MB, the entire regression).
// Staging loads+stores now both sit at the END of the iteration in one
// if-block: live range ~4 instrs, no spill. Dbuf invariant unchanged
// (stores still hit buf cur^1 after this iter's reads of buf cur).

#define NB   4
#define SQ   4096
#define SKV  4096
#define DH   64
#define L2E  1.44269504088896340736f

typedef _Float16 half8 __attribute__((ext_vector_type(8)));
typedef _Float16 half4 __attribute__((ext_vector_type(4)));
typedef _Float16 half2v __attribute__((ext_vector_type(2)));
typedef float f32x4 __attribute__((ext_vector_type(4)));
typedef unsigned short u16;

#define MFMA16(a, b, c) __builtin_amdgcn_mfma_f32_16x16x16f16((a), (b), (c), 0, 0, 0)
#define MFMA32(a, b, c) __builtin_amdgcn_mfma_f32_16x16x32_f16((a), (b), (c), 0, 0, 0)

__device__ __forceinline__ u16 f2h(float f) {
  _Float16 h = (_Float16)f;
  return __builtin_bit_cast(u16, h);
}
__device__ __forceinline__ half2v pkrtz(float a, float b) {
  return __builtin_bit_cast(half2v, __builtin_amdgcn_cvt_pkrtz(a, b));
}

// ---------------------------------------------------------------- prep ----
// V fp32 -> vh fp16 [b][j][d] and vt fp16 [b][d][j]. grid NB*256, 256 thr.
__global__ __launch_bounds__(256) void prep_kernel(
    const float* __restrict__ V, u16* __restrict__ vh, u16* __restrict__ vt) {
  __shared__ u16 ldsT[16 * 72];
  int blk = blockIdx.x;
  int b   = blk >> 8;
  int rem = blk & 255;
  int j0  = (rem >> 2) << 6;   // kv tile base
  int d0  = (rem & 3) << 4;    // d tile base
  int t   = threadIdx.x;
  int j   = t >> 2;            // 0..63
  int dc  = (t & 3) << 2;      // 0,4,8,12

  const float* src = V + ((size_t)(b * SKV) + j0 + j) * DH + d0 + dc;
  float4 v4 = *(const float4*)src;
  u16 h[4] = {f2h(v4.x), f2h(v4.y), f2h(v4.z), f2h(v4.w)};
  unsigned p0 = (unsigned)h[0] | ((unsigned)h[1] << 16);
  unsigned p1 = (unsigned)h[2] | ((unsigned)h[3] << 16);
  size_t go = ((size_t)(b * SKV) + j0 + j) * DH + d0 + dc;
  *(uint2*)(vh + go) = make_uint2(p0, p1);

#pragma unroll
  for (int k = 0; k < 4; ++k) ldsT[(dc + k) * 72 + j] = h[k];
  __syncthreads();

  int dl = t >> 4;             // 0..15
  int jc = (t & 15) << 2;      // 0..60
  u16 tr[4];
#pragma unroll
  for (int k = 0; k < 4; ++k) tr[k] = ldsT[dl * 72 + jc + k];
  unsigned q0 = (unsigned)tr[0] | ((unsigned)tr[1] << 16);
  unsigned q1 = (unsigned)tr[2] | ((unsigned)tr[3] << 16);
  *(uint2*)(vt + ((size_t)(b * DH) + d0 + dl) * SKV + j0 + jc) = make_uint2(q0, q1);
}

// ---------------------------------------------------------------- attn ----
// grid NB*32*S blocks, 256 threads = 4 waves * 32 q-cols (2 sets of 16).
__global__ __launch_bounds__(256, 4) void attn_kernel(
    const float* __restrict__ Q,
    const u16* __restrict__ vh,
    const u16* __restrict__ vt,
    u16* __restrict__ po,    // [NB*32*S][128 q][64 d] fp16 unnormalized O
    float* __restrict__ pm,  // [NB*32*S][128] running max (log2 domain)
    float* __restrict__ pl,  // [NB*32*S][128] running sum
    int S, int kvLen) {
  // [buf][0 = V tile [kv][d], 1 = V^T tile [d][kv]], stride 72 (pad)
  __shared__ __align__(16) u16 lds[2][2][64 * 72];

  int blk  = blockIdx.x;
  int tile = blk / S;          // b*32 + qtile
  int s    = blk - tile * S;
  int b    = tile >> 5;
  int q0   = (tile & 31) << 7;
  int kv0  = s * kvLen;
  int t    = threadIdx.x;
  int wave = t >> 6;
  int lane = t & 63;
  int col  = lane & 15;
  int quad = lane >> 4;
  int qw   = q0 + (wave << 5);

  // ---- Q fragments as B-operand (n=lane&15=q, k=quad*8+j), log2e folded
  half8 qf[2][2];
#pragma unroll
  for (int set = 0; set < 2; ++set) {
#pragma unroll
    for (int kc = 0; kc < 2; ++kc) {
      const float* qp = Q + ((size_t)(b * SQ) + qw + set * 16 + col) * DH +
                        kc * 32 + (quad << 3);
      float4 a0 = *(const float4*)qp;
      float4 a1 = *(const float4*)(qp + 4);
      half8 h;
      h[0] = (_Float16)(a0.x * L2E); h[1] = (_Float16)(a0.y * L2E);
      h[2] = (_Float16)(a0.z * L2E); h[3] = (_Float16)(a0.w * L2E);
      h[4] = (_Float16)(a1.x * L2E); h[5] = (_Float16)(a1.y * L2E);
      h[6] = (_Float16)(a1.z * L2E); h[7] = (_Float16)(a1.w * L2E);
      qf[set][kc] = h;
    }
  }

  f32x4 o[2][4];               // O^T frags: [set][d-block], row=d, col=q
  float m_r[2] = {-1e30f, -1e30f};
  float l_r[2] = {0.f, 0.f};   // per-lane partial (this quad's kv rows)
#pragma unroll
  for (int set = 0; set < 2; ++set)
#pragma unroll
    for (int nf = 0; nf < 4; ++nf) o[set][nf] = (f32x4){0.f, 0.f, 0.f, 0.f};

  int sr = t >> 2;             // staging row 0..63
  int sc = (t & 3) << 4;       // staging col chunk
  const u16* gv  = vh + (size_t)(b * SKV) * DH;
  const u16* gvt = vt + (size_t)(b * DH) * SKV;
  int l0 = sr * 72 + sc;

  // prologue: stage tile 0 into buf 0
  {
    size_t g  = (size_t)(kv0 + sr) * DH + sc;
    size_t gt = (size_t)sr * SKV + kv0 + sc;
    *(uint4*)(&lds[0][0][l0])     = *(const uint4*)(gv + g);
    *(uint4*)(&lds[0][0][l0 + 8]) = *(const uint4*)(gv + g + 8);
    *(uint4*)(&lds[0][1][l0])     = *(const uint4*)(gvt + gt);
    *(uint4*)(&lds[0][1][l0 + 8]) = *(const uint4*)(gvt + gt + 8);
  }

  int nIter = kvLen >> 6;
  int cur = 0;
  for (int it = 0; it < nIter; ++it) {
    __syncthreads();           // buf(cur) ready; all waves done with buf(cur^1)

    const u16* sv  = &lds[cur][0][0];
    const u16* svt = &lds[cur][1][0];

    // ---- S^T = V @ Q^T (A = V tile from LDS, B = Q regs)
    f32x4 sf[2][4];
#pragma unroll
    for (int set = 0; set < 2; ++set)
#pragma unroll
      for (int nf = 0; nf < 4; ++nf) sf[set][nf] = (f32x4){0.f, 0.f, 0.f, 0.f};
#pragma unroll
    for (int nf = 0; nf < 4; ++nf) {
#pragma unroll
      for (int kc = 0; kc < 2; ++kc) {
        half8 av = *(const half8*)(sv + (nf * 16 + col) * 72 + kc * 32 + (quad << 3));
        sf[0][nf] = MFMA32(av, qf[0][kc], sf[0][nf]);
        sf[1][nf] = MFMA32(av, qf[1][kc], sf[1][nf]);
      }
    }

    // ---- online softmax (per-lane scalar state) + direct P^T B-frags
    half4 pf[2][4];
#pragma unroll
    for (int set = 0; set < 2; ++set) {
      float tm = sf[set][0][0];
#pragma unroll
      for (int nf = 0; nf < 4; ++nf)
#pragma unroll
        for (int r = 0; r < 4; ++r) tm = fmaxf(tm, sf[set][nf][r]);
      tm = fmaxf(tm, __shfl_xor(tm, 16, 64));
      tm = fmaxf(tm, __shfl_xor(tm, 32, 64));
      float mn = fmaxf(m_r[set], tm);
      float al = exp2f(m_r[set] - mn);
      m_r[set] = mn;
      float rs = 0.f;
#pragma unroll
      for (int nf = 0; nf < 4; ++nf) {
        float p0 = exp2f(sf[set][nf][0] - mn);
        float p1 = exp2f(sf[set][nf][1] - mn);
        float p2 = exp2f(sf[set][nf][2] - mn);
        float p3 = exp2f(sf[set][nf][3] - mn);
        rs += (p0 + p1) + (p2 + p3);
        half2v lo = pkrtz(p0, p1);
        half2v hi = pkrtz(p2, p3);
        pf[set][nf] = __builtin_shufflevector(lo, hi, 0, 1, 2, 3);
      }
      l_r[set] = l_r[set] * al + rs;
#pragma unroll
      for (int nf = 0; nf < 4; ++nf)
#pragma unroll
        for (int r = 0; r < 4; ++r) o[set][nf][r] *= al;
    }

    // ---- O^T += V^T @ P^T (K=16; P^T frags straight from C-layout)
#pragma unroll
    for (int kc4 = 0; kc4 < 4; ++kc4) {
#pragma unroll
      for (int nf2 = 0; nf2 < 4; ++nf2) {
        half4 avt = *(const half4*)(svt + (nf2 * 16 + col) * 72 + kc4 * 16 + (quad << 2));
        o[0][nf2] = MFMA16(avt, pf[0][kc4], o[0][nf2]);
        o[1][nf2] = MFMA16(avt, pf[1][kc4], o[1][nf2]);
      }
    }

    // ---- stage next tile at END of iter: load->store live range is tiny
    // (R6 loaded here-equivalents BEFORE compute -> 16 VGPRs live across
    // the body -> scratch spill. This placement is the whole R7 fix.)
    if ((it + 1) < nIter) {
      int j0n = kv0 + ((it + 1) << 6);
      size_t g  = (size_t)(j0n + sr) * DH + sc;
      size_t gt = (size_t)sr * SKV + j0n + sc;
      uint4 a0 = *(const uint4*)(gv + g);
      uint4 a1 = *(const uint4*)(gv + g + 8);
      uint4 c0 = *(const uint4*)(gvt + gt);
      uint4 c1 = *(const uint4*)(gvt + gt + 8);
      u16* dv  = &lds[cur ^ 1][0][0];
      u16* dvt = &lds[cur ^ 1][1][0];
      *(uint4*)(dv + l0)      = a0;
      *(uint4*)(dv + l0 + 8)  = a1;
      *(uint4*)(dvt + l0)     = c0;
      *(uint4*)(dvt + l0 + 8) = c1;
    }
    cur ^= 1;
  }

  // ---- epilogue: finish l across quads, transpose O^T -> po[q][d] via LDS
#pragma unroll
  for (int set = 0; set < 2; ++set) {
    l_r[set] += __shfl_xor(l_r[set], 16, 64);
    l_r[set] += __shfl_xor(l_r[set], 32, 64);
  }
  int pidx = tile * S + s;
  if (quad == 0) {
#pragma unroll
    for (int set = 0; set < 2; ++set) {
      int row = (wave << 5) + set * 16 + col;
      pm[(size_t)pidx * 128 + row] = m_r[set];
      pl[(size_t)pidx * 128 + row] = l_r[set];
    }
  }

  __syncthreads();             // done with tile buffers; reuse as 128x72 tile
  u16* tp = &lds[0][0][0];
#pragma unroll
  for (int set = 0; set < 2; ++set) {
    int q = (wave << 5) + set * 16 + col;
#pragma unroll
    for (int nf2 = 0; nf2 < 4; ++nf2) {
#pragma unroll
      for (int r2 = 0; r2 < 4; r2 += 2) {
        unsigned pk = (unsigned)f2h(o[set][nf2][r2]) |
                      ((unsigned)f2h(o[set][nf2][r2 + 1]) << 16);
        int d = nf2 * 16 + (quad << 2) + r2;
        *(unsigned*)(tp + q * 72 + d) = pk;
      }
    }
  }
  __syncthreads();
  {
    u16* pob = po + (size_t)pidx * 128 * 64;
    int q = t >> 1, hc = (t & 1) << 5;
    uint4 x0 = *(const uint4*)(tp + q * 72 + hc);
    uint4 x1 = *(const uint4*)(tp + q * 72 + hc + 8);
    uint4 x2 = *(const uint4*)(tp + q * 72 + hc + 16);
    uint4 x3 = *(const uint4*)(tp + q * 72 + hc + 24);
    *(uint4*)(pob + q * 64 + hc)      = x0;
    *(uint4*)(pob + q * 64 + hc + 8)  = x1;
    *(uint4*)(pob + q * 64 + hc + 16) = x2;
    *(uint4*)(pob + q * 64 + hc + 24) = x3;
  }
}

// ------------------------------------------------------------- combine ----
// grid NB*SQ/32 blocks, 256 threads; thread = (row, 8-d chunk).
__global__ __launch_bounds__(256) void combine_kernel(
    const u16* __restrict__ po,
    const float* __restrict__ pm,
    const float* __restrict__ pl,
    float* __restrict__ out, int S) {
  int t    = threadIdx.x;
  int rowg = blockIdx.x * 32 + (t >> 3);
  int tile = rowg >> 7;
  int row  = rowg & 127;
  int dc   = (t & 7) << 3;

  float mv[8], lv[8];
  float M = -1e30f;
  for (int s = 0; s < S; ++s) {
    mv[s] = pm[(size_t)(tile * S + s) * 128 + row];
    lv[s] = pl[(size_t)(tile * S + s) * 128 + row];
    M = fmaxf(M, mv[s]);
  }
  float L = 0.f, w[8];
  for (int s = 0; s < S; ++s) {
    w[s] = exp2f(mv[s] - M);
    L += lv[s] * w[s];
  }
  float acc[8] = {0.f, 0.f, 0.f, 0.f, 0.f, 0.f, 0.f, 0.f};
  for (int s = 0; s < S; ++s) {
    const u16* p = po + (size_t)(tile * S + s) * 8192 + row * 64 + dc;
    uint4 raw = *(const uint4*)p;
    half8 x = __builtin_bit_cast(half8, raw);
#pragma unroll
    for (int k = 0; k < 8; ++k) acc[k] += w[s] * (float)x[k];
  }
  float invL = 1.0f / L;
  float* op = out + (size_t)rowg * 64 + dc;
  f32x4 o0 = (f32x4){acc[0], acc[1], acc[2], acc[3]};
  f32x4 o1 = (f32x4){acc[4], acc[5], acc[6], acc[7]};
  *(f32x4*)op       = o0 * invL;
  *(f32x4*)(op + 4) = o1 * invL;
}

// -------------------------------------------------------------- launch ----
extern "C" void kernel_launch(void* const* d_in, const int* in_sizes, int n_in,
                              void* d_out, int out_size, void* d_ws, size_t ws_size,
                              hipStream_t stream) {
  const float* Q = (const float*)d_in[0];
  const float* V = (const float*)d_in[1];
  float* out = (float*)d_out;

  const size_t convBytes = (size_t)2 * NB * SKV * DH * 2;  // vh+vt = 4 MB
  auto partBytes = [](int S) {
    return (size_t)NB * 32 * S * ((size_t)128 * 64 * 2 + 128 * 8);
  };
  int S = 8;
  while (S > 1 && ws_size < convBytes + partBytes(S)) S >>= 1;
  int kvLen = SKV / S;

  u16* vh = (u16*)d_ws;
  u16* vt = vh + (size_t)NB * SKV * DH;
  u16* po = vt + (size_t)NB * SKV * DH;
  float* pm = (float*)(po + (size_t)NB * 32 * S * 128 * 64);
  float* pl = pm + (size_t)NB * 32 * S * 128;

  prep_kernel<<<NB * 256, 256, 0, stream>>>(V, vh, vt);
  attn_kernel<<<NB * 32 * S, 256, 0, stream>>>(Q, vh, vt, po, pm, pl, S, kvLen);
  combine_kernel<<<NB * SQ / 32, 256, 0, stream>>>(po, pm, pl, out, S);
}

// Round 9
// 108.351 us; speedup vs baseline: 1.1781x; 1.0328x over previous
//
#include <hip/hip_runtime.h>

// AttentionLayer: out = softmax(Q @ V^T) @ V ; B=4, SQ=SKV=4096, D=64, fp32.
//
// R4-R7: transposed formulation (S^T = V·Q^T; exp2 C-frags feed K=16 PV MFMA
// directly as B-operand; per-lane scalar softmax; double-buffered LDS, one
// barrier/iter). R7 proved the WRITE_SIZE blowup was register spill from
// launch_bounds(256,4)'s 128-reg cap.
// R8: restore the proper pipeline (staging loads at TOP of iter, stores at
// END -> full compute body hides global latency) and relax to
// __launch_bounds__(256,3) (cap ~170) so the 16 staged VGPRs + qf/o/sf/pf
// fit with zero spill. Trades possibly 4->3 blocks/CU for no scratch traffic
// and no exposed load latency at the barrier.

#define NB   4
#define SQ   4096
#define SKV  4096
#define DH   64
#define L2E  1.44269504088896340736f

typedef _Float16 half8 __attribute__((ext_vector_type(8)));
typedef _Float16 half4 __attribute__((ext_vector_type(4)));
typedef _Float16 half2v __attribute__((ext_vector_type(2)));
typedef float f32x4 __attribute__((ext_vector_type(4)));
typedef unsigned short u16;

#define MFMA16(a, b, c) __builtin_amdgcn_mfma_f32_16x16x16f16((a), (b), (c), 0, 0, 0)
#define MFMA32(a, b, c) __builtin_amdgcn_mfma_f32_16x16x32_f16((a), (b), (c), 0, 0, 0)

__device__ __forceinline__ u16 f2h(float f) {
  _Float16 h = (_Float16)f;
  return __builtin_bit_cast(u16, h);
}
__device__ __forceinline__ half2v pkrtz(float a, float b) {
  return __builtin_bit_cast(half2v, __builtin_amdgcn_cvt_pkrtz(a, b));
}

// ---------------------------------------------------------------- prep ----
// V fp32 -> vh fp16 [b][j][d] and vt fp16 [b][d][j]. grid NB*256, 256 thr.
__global__ __launch_bounds__(256) void prep_kernel(
    const float* __restrict__ V, u16* __restrict__ vh, u16* __restrict__ vt) {
  __shared__ u16 ldsT[16 * 72];
  int blk = blockIdx.x;
  int b   = blk >> 8;
  int rem = blk & 255;
  int j0  = (rem >> 2) << 6;   // kv tile base
  int d0  = (rem & 3) << 4;    // d tile base
  int t   = threadIdx.x;
  int j   = t >> 2;            // 0..63
  int dc  = (t & 3) << 2;      // 0,4,8,12

  const float* src = V + ((size_t)(b * SKV) + j0 + j) * DH + d0 + dc;
  float4 v4 = *(const float4*)src;
  u16 h[4] = {f2h(v4.x), f2h(v4.y), f2h(v4.z), f2h(v4.w)};
  unsigned p0 = (unsigned)h[0] | ((unsigned)h[1] << 16);
  unsigned p1 = (unsigned)h[2] | ((unsigned)h[3] << 16);
  size_t go = ((size_t)(b * SKV) + j0 + j) * DH + d0 + dc;
  *(uint2*)(vh + go) = make_uint2(p0, p1);

#pragma unroll
  for (int k = 0; k < 4; ++k) ldsT[(dc + k) * 72 + j] = h[k];
  __syncthreads();

  int dl = t >> 4;             // 0..15
  int jc = (t & 15) << 2;      // 0..60
  u16 tr[4];
#pragma unroll
  for (int k = 0; k < 4; ++k) tr[k] = ldsT[dl * 72 + jc + k];
  unsigned q0 = (unsigned)tr[0] | ((unsigned)tr[1] << 16);
  unsigned q1 = (unsigned)tr[2] | ((unsigned)tr[3] << 16);
  *(uint2*)(vt + ((size_t)(b * DH) + d0 + dl) * SKV + j0 + jc) = make_uint2(q0, q1);
}

// ---------------------------------------------------------------- attn ----
// grid NB*32*S blocks, 256 threads = 4 waves * 32 q-cols (2 sets of 16).
__global__ __launch_bounds__(256, 3) void attn_kernel(
    const float* __restrict__ Q,
    const u16* __restrict__ vh,
    const u16* __restrict__ vt,
    u16* __restrict__ po,    // [NB*32*S][128 q][64 d] fp16 unnormalized O
    float* __restrict__ pm,  // [NB*32*S][128] running max (log2 domain)
    float* __restrict__ pl,  // [NB*32*S][128] running sum
    int S, int kvLen) {
  // [buf][0 = V tile [kv][d], 1 = V^T tile [d][kv]], stride 72 (pad)
  __shared__ __align__(16) u16 lds[2][2][64 * 72];

  int blk  = blockIdx.x;
  int tile = blk / S;          // b*32 + qtile
  int s    = blk - tile * S;
  int b    = tile >> 5;
  int q0   = (tile & 31) << 7;
  int kv0  = s * kvLen;
  int t    = threadIdx.x;
  int wave = t >> 6;
  int lane = t & 63;
  int col  = lane & 15;
  int quad = lane >> 4;
  int qw   = q0 + (wave << 5);

  // ---- Q fragments as B-operand (n=lane&15=q, k=quad*8+j), log2e folded
  half8 qf[2][2];
#pragma unroll
  for (int set = 0; set < 2; ++set) {
#pragma unroll
    for (int kc = 0; kc < 2; ++kc) {
      const float* qp = Q + ((size_t)(b * SQ) + qw + set * 16 + col) * DH +
                        kc * 32 + (quad << 3);
      float4 a0 = *(const float4*)qp;
      float4 a1 = *(const float4*)(qp + 4);
      half8 h;
      h[0] = (_Float16)(a0.x * L2E); h[1] = (_Float16)(a0.y * L2E);
      h[2] = (_Float16)(a0.z * L2E); h[3] = (_Float16)(a0.w * L2E);
      h[4] = (_Float16)(a1.x * L2E); h[5] = (_Float16)(a1.y * L2E);
      h[6] = (_Float16)(a1.z * L2E); h[7] = (_Float16)(a1.w * L2E);
      qf[set][kc] = h;
    }
  }

  f32x4 o[2][4];               // O^T frags: [set][d-block], row=d, col=q
  float m_r[2] = {-1e30f, -1e30f};
  float l_r[2] = {0.f, 0.f};   // per-lane partial (this quad's kv rows)
#pragma unroll
  for (int set = 0; set < 2; ++set)
#pragma unroll
    for (int nf = 0; nf < 4; ++nf) o[set][nf] = (f32x4){0.f, 0.f, 0.f, 0.f};

  int sr = t >> 2;             // staging row 0..63
  int sc = (t & 3) << 4;       // staging col chunk
  const u16* gv  = vh + (size_t)(b * SKV) * DH;
  const u16* gvt = vt + (size_t)(b * DH) * SKV;
  int l0 = sr * 72 + sc;

  // prologue: stage tile 0 into buf 0
  {
    size_t g  = (size_t)(kv0 + sr) * DH + sc;
    size_t gt = (size_t)sr * SKV + kv0 + sc;
    *(uint4*)(&lds[0][0][l0])     = *(const uint4*)(gv + g);
    *(uint4*)(&lds[0][0][l0 + 8]) = *(const uint4*)(gv + g + 8);
    *(uint4*)(&lds[0][1][l0])     = *(const uint4*)(gvt + gt);
    *(uint4*)(&lds[0][1][l0 + 8]) = *(const uint4*)(gvt + gt + 8);
  }

  int nIter = kvLen >> 6;
  int cur = 0;
  for (int it = 0; it < nIter; ++it) {
    __syncthreads();           // buf(cur) ready; all waves done with buf(cur^1)

    // ---- issue next-tile loads NOW: whole compute body hides the latency
    // (fits without spill thanks to launch_bounds(256,3); the 128-cap of
    // (256,4) is what forced R7's end-of-iter placement)
    uint4 a0, a1, c0, c1;
    bool more = (it + 1) < nIter;
    if (more) {
      int j0n = kv0 + ((it + 1) << 6);
      size_t g  = (size_t)(j0n + sr) * DH + sc;
      size_t gt = (size_t)sr * SKV + j0n + sc;
      a0 = *(const uint4*)(gv + g);
      a1 = *(const uint4*)(gv + g + 8);
      c0 = *(const uint4*)(gvt + gt);
      c1 = *(const uint4*)(gvt + gt + 8);
    }

    const u16* sv  = &lds[cur][0][0];
    const u16* svt = &lds[cur][1][0];

    // ---- S^T = V @ Q^T (A = V tile from LDS, B = Q regs)
    f32x4 sf[2][4];
#pragma unroll
    for (int set = 0; set < 2; ++set)
#pragma unroll
      for (int nf = 0; nf < 4; ++nf) sf[set][nf] = (f32x4){0.f, 0.f, 0.f, 0.f};
#pragma unroll
    for (int nf = 0; nf < 4; ++nf) {
#pragma unroll
      for (int kc = 0; kc < 2; ++kc) {
        half8 av = *(const half8*)(sv + (nf * 16 + col) * 72 + kc * 32 + (quad << 3));
        sf[0][nf] = MFMA32(av, qf[0][kc], sf[0][nf]);
        sf[1][nf] = MFMA32(av, qf[1][kc], sf[1][nf]);
      }
    }

    // ---- online softmax (per-lane scalar state) + direct P^T B-frags
    half4 pf[2][4];
#pragma unroll
    for (int set = 0; set < 2; ++set) {
      float tm = sf[set][0][0];
#pragma unroll
      for (int nf = 0; nf < 4; ++nf)
#pragma unroll
        for (int r = 0; r < 4; ++r) tm = fmaxf(tm, sf[set][nf][r]);
      tm = fmaxf(tm, __shfl_xor(tm, 16, 64));
      tm = fmaxf(tm, __shfl_xor(tm, 32, 64));
      float mn = fmaxf(m_r[set], tm);
      float al = exp2f(m_r[set] - mn);
      m_r[set] = mn;
      float rs = 0.f;
#pragma unroll
      for (int nf = 0; nf < 4; ++nf) {
        float p0 = exp2f(sf[set][nf][0] - mn);
        float p1 = exp2f(sf[set][nf][1] - mn);
        float p2 = exp2f(sf[set][nf][2] - mn);
        float p3 = exp2f(sf[set][nf][3] - mn);
        rs += (p0 + p1) + (p2 + p3);
        half2v lo = pkrtz(p0, p1);
        half2v hi = pkrtz(p2, p3);
        pf[set][nf] = __builtin_shufflevector(lo, hi, 0, 1, 2, 3);
      }
      l_r[set] = l_r[set] * al + rs;
#pragma unroll
      for (int nf = 0; nf < 4; ++nf)
#pragma unroll
        for (int r = 0; r < 4; ++r) o[set][nf][r] *= al;
    }

    // ---- O^T += V^T @ P^T (K=16; P^T frags straight from C-layout)
#pragma unroll
    for (int kc4 = 0; kc4 < 4; ++kc4) {
#pragma unroll
      for (int nf2 = 0; nf2 < 4; ++nf2) {
        half4 avt = *(const half4*)(svt + (nf2 * 16 + col) * 72 + kc4 * 16 + (quad << 2));
        o[0][nf2] = MFMA16(avt, pf[0][kc4], o[0][nf2]);
        o[1][nf2] = MFMA16(avt, pf[1][kc4], o[1][nf2]);
      }
    }

    // ---- write staged regs -> other buffer (loads long since landed)
    if (more) {
      u16* dv  = &lds[cur ^ 1][0][0];
      u16* dvt = &lds[cur ^ 1][1][0];
      *(uint4*)(dv + l0)      = a0;
      *(uint4*)(dv + l0 + 8)  = a1;
      *(uint4*)(dvt + l0)     = c0;
      *(uint4*)(dvt + l0 + 8) = c1;
    }
    cur ^= 1;
  }

  // ---- epilogue: finish l across quads, transpose O^T -> po[q][d] via LDS
#pragma unroll
  for (int set = 0; set < 2; ++set) {
    l_r[set] += __shfl_xor(l_r[set], 16, 64);
    l_r[set] += __shfl_xor(l_r[set], 32, 64);
  }
  int pidx = tile * S + s;
  if (quad == 0) {
#pragma unroll
    for (int set = 0; set < 2; ++set) {
      int row = (wave << 5) + set * 16 + col;
      pm[(size_t)pidx * 128 + row] = m_r[set];
      pl[(size_t)pidx * 128 + row] = l_r[set];
    }
  }

  __syncthreads();             // done with tile buffers; reuse as 128x72 tile
  u16* tp = &lds[0][0][0];
#pragma unroll
  for (int set = 0; set < 2; ++set) {
    int q = (wave << 5) + set * 16 + col;
#pragma unroll
    for (int nf2 = 0; nf2 < 4; ++nf2) {
#pragma unroll
      for (int r2 = 0; r2 < 4; r2 += 2) {
        unsigned pk = (unsigned)f2h(o[set][nf2][r2]) |
                      ((unsigned)f2h(o[set][nf2][r2 + 1]) << 16);
        int d = nf2 * 16 + (quad << 2) + r2;
        *(unsigned*)(tp + q * 72 + d) = pk;
      }
    }
  }
  __syncthreads();
  {
    u16* pob = po + (size_t)pidx * 128 * 64;
    int q = t >> 1, hc = (t & 1) << 5;
    uint4 x0 = *(const uint4*)(tp + q * 72 + hc);
    uint4 x1 = *(const uint4*)(tp + q * 72 + hc + 8);
    uint4 x2 = *(const uint4*)(tp + q * 72 + hc + 16);
    uint4 x3 = *(const uint4*)(tp + q * 72 + hc + 24);
    *(uint4*)(pob + q * 64 + hc)      = x0;
    *(uint4*)(pob + q * 64 + hc + 8)  = x1;
    *(uint4*)(pob + q * 64 + hc + 16) = x2;
    *(uint4*)(pob + q * 64 + hc + 24) = x3;
  }
}

// ------------------------------------------------------------- combine ----
// grid NB*SQ/32 blocks, 256 threads; thread = (row, 8-d chunk).
__global__ __launch_bounds__(256) void combine_kernel(
    const u16* __restrict__ po,
    const float* __restrict__ pm,
    const float* __restrict__ pl,
    float* __restrict__ out, int S) {
  int t    = threadIdx.x;
  int rowg = blockIdx.x * 32 + (t >> 3);
  int tile = rowg >> 7;
  int row  = rowg & 127;
  int dc   = (t & 7) << 3;

  float mv[8], lv[8];
  float M = -1e30f;
  for (int s = 0; s < S; ++s) {
    mv[s] = pm[(size_t)(tile * S + s) * 128 + row];
    lv[s] = pl[(size_t)(tile * S + s) * 128 + row];
    M = fmaxf(M, mv[s]);
  }
  float L = 0.f, w[8];
  for (int s = 0; s < S; ++s) {
    w[s] = exp2f(mv[s] - M);
    L += lv[s] * w[s];
  }
  float acc[8] = {0.f, 0.f, 0.f, 0.f, 0.f, 0.f, 0.f, 0.f};
  for (int s = 0; s < S; ++s) {
    const u16* p = po + (size_t)(tile * S + s) * 8192 + row * 64 + dc;
    uint4 raw = *(const uint4*)p;
    half8 x = __builtin_bit_cast(half8, raw);
#pragma unroll
    for (int k = 0; k < 8; ++k) acc[k] += w[s] * (float)x[k];
  }
  float invL = 1.0f / L;
  float* op = out + (size_t)rowg * 64 + dc;
  f32x4 o0 = (f32x4){acc[0], acc[1], acc[2], acc[3]};
  f32x4 o1 = (f32x4){acc[4], acc[5], acc[6], acc[7]};
  *(f32x4*)op       = o0 * invL;
  *(f32x4*)(op + 4) = o1 * invL;
}

// -------------------------------------------------------------- launch ----
extern "C" void kernel_launch(void* const* d_in, const int* in_sizes, int n_in,
                              void* d_out, int out_size, void* d_ws, size_t ws_size,
                              hipStream_t stream) {
  const float* Q = (const float*)d_in[0];
  const float* V = (const float*)d_in[1];
  float* out = (float*)d_out;

  const size_t convBytes = (size_t)2 * NB * SKV * DH * 2;  // vh+vt = 4 MB
  auto partBytes = [](int S) {
    return (size_t)NB * 32 * S * ((size_t)128 * 64 * 2 + 128 * 8);
  };
  int S = 8;
  while (S > 1 && ws_size < convBytes + partBytes(S)) S >>= 1;
  int kvLen = SKV / S;

  u16* vh = (u16*)d_ws;
  u16* vt = vh + (size_t)NB * SKV * DH;
  u16* po = vt + (size_t)NB * SKV * DH;
  float* pm = (float*)(po + (size_t)NB * 32 * S * 128 * 64);
  float* pl = pm + (size_t)NB * 32 * S * 128;

  prep_kernel<<<NB * 256, 256, 0, stream>>>(V, vh, vt);
  attn_kernel<<<NB * 32 * S, 256, 0, stream>>>(Q, vh, vt, po, pm, pl, S, kvLen);
  combine_kernel<<<NB * SQ / 32, 256, 0, stream>>>(po, pm, pl, out, S);
}